// Round 1
// 514.209 us; speedup vs baseline: 1.0534x; 1.0534x over previous
//
#include <hip/hip_runtime.h>

// Problem constants
#define B_   8
#define NT_  512
#define NC_  2048
#define EMB_ 512
#define H_   8
// DK = DV = 64

typedef __attribute__((ext_vector_type(8))) short bf16x8;
typedef __attribute__((ext_vector_type(4))) float f32x4;

__device__ __forceinline__ unsigned short f2bf(float x) {
    unsigned u = __float_as_uint(x);
    u += 0x7fffu + ((u >> 16) & 1u);          // RNE
    return (unsigned short)(u >> 16);
}
__device__ __forceinline__ float b2f(unsigned short h) {
    return __uint_as_float(((unsigned)h) << 16);
}

// XOR-swizzled LDS tile index: rows of 64 bf16, 8-elem (16B) granules.
__device__ __forceinline__ int swz(int row, int col) {
    return row * 64 + ((((col >> 3) ^ row) & 7) << 3) + (col & 7);
}

// MFMA operand fragment from a swizzled 64-col tile:
// elem j of lane L holds T[rowbase + (L&15)][kq + (L>>4)*8 + j]
__device__ __forceinline__ bf16x8 ldfrag(const unsigned short* t, int rowbase, int kq) {
    int lane = threadIdx.x & 63;
    int m = rowbase + (lane & 15);
    int k = kq + ((lane >> 4) << 3);
    return *(const bf16x8*)(t + swz(m, k));
}

// Stage a 64-col x (NCH*32)-row tile into swizzled LDS from fp32 global (cvt bf16).
template<int NCH>
__device__ __forceinline__ void stage_f32(unsigned short* tile, const float* src, int ld) {
    int tid = threadIdx.x;
#pragma unroll
    for (int i = 0; i < NCH; i++) {
        int ch  = tid + i * 256;
        int row = ch >> 3, c8 = ch & 7;
        const float4* p = (const float4*)(src + (size_t)row * ld + c8 * 8);
        float4 a = p[0], b = p[1];
        uint4 u;
        u.x = (unsigned)f2bf(a.x) | ((unsigned)f2bf(a.y) << 16);
        u.y = (unsigned)f2bf(a.z) | ((unsigned)f2bf(a.w) << 16);
        u.z = (unsigned)f2bf(b.x) | ((unsigned)f2bf(b.y) << 16);
        u.w = (unsigned)f2bf(b.z) | ((unsigned)f2bf(b.w) << 16);
        *(uint4*)(tile + row * 64 + (((c8 ^ row) & 7) << 3)) = u;
    }
}
// Same, from bf16 global.
template<int NCH>
__device__ __forceinline__ void stage_bf(unsigned short* tile, const unsigned short* src, int ld) {
    int tid = threadIdx.x;
#pragma unroll
    for (int i = 0; i < NCH; i++) {
        int ch  = tid + i * 256;
        int row = ch >> 3, c8 = ch & 7;
        uint4 u = *(const uint4*)(src + (size_t)row * ld + c8 * 8);
        *(uint4*)(tile + row * 64 + (((c8 ^ row) & 7) << 3)) = u;
    }
}

// ---------------------------------------------------------------------------
// C = A(Mx512) @ W(512x512)^T + bias, 64x64 block tile, 4 waves.
// MODE 0: bf16 out, head-major, ROW-NORMALIZED (q/k projections; 64-n tile == one head)
// MODE 1: bf16 out, d-major transposed (v projection)
// MODE 2: fp32 out, row-major (final out projection)
// ---------------------------------------------------------------------------
template<int MODE, bool ABF>
__global__ __launch_bounds__(256) void gemm512(const void* A, const float* W,
                                               const float* bias, void* dst, int sh)
{
    __shared__ unsigned short As[64 * 64];
    __shared__ unsigned short Bs[64 * 64];
    int r0 = blockIdx.x * 64;
    int n0 = blockIdx.y * 64;
    int tid = threadIdx.x;
    int w = tid >> 6, quad = (tid >> 4) & 3, l16 = tid & 15;
    f32x4 acc[4] = {};

    for (int k0 = 0; k0 < 512; k0 += 64) {
        __syncthreads();
        if (ABF) stage_bf<2>(As, (const unsigned short*)A + (size_t)r0 * 512 + k0, 512);
        else     stage_f32<2>(As, (const float*)A + (size_t)r0 * 512 + k0, 512);
        stage_f32<2>(Bs, W + (size_t)n0 * 512 + k0, 512);
        __syncthreads();
#pragma unroll
        for (int ks = 0; ks < 2; ks++) {
            bf16x8 af = ldfrag(As, 16 * w, 32 * ks);
#pragma unroll
            for (int nt = 0; nt < 4; nt++) {
                bf16x8 bfr = ldfrag(Bs, 16 * nt, 32 * ks);
                acc[nt] = __builtin_amdgcn_mfma_f32_16x16x32_bf16(af, bfr, acc[nt], 0, 0, 0);
            }
        }
    }

    float vals[4][4];
    float bn[4];
#pragma unroll
    for (int nt = 0; nt < 4; nt++) bn[nt] = bias[n0 + nt * 16 + l16];
#pragma unroll
    for (int nt = 0; nt < 4; nt++)
#pragma unroll
        for (int r = 0; r < 4; r++) vals[nt][r] = acc[nt][r] + bn[nt];

    if (MODE == 0) {
        // fused row-normalize: row's 64 d-values live across l16 group x 4 nt regs
#pragma unroll
        for (int r = 0; r < 4; r++) {
            float ss = 0.f;
#pragma unroll
            for (int nt = 0; nt < 4; nt++) ss += vals[nt][r] * vals[nt][r];
#pragma unroll
            for (int m = 1; m <= 8; m <<= 1) ss += __shfl_xor(ss, m, 64);
            float sc = rsqrtf(fmaxf(ss, 1e-24f));
#pragma unroll
            for (int nt = 0; nt < 4; nt++) vals[nt][r] *= sc;
        }
    }

#pragma unroll
    for (int nt = 0; nt < 4; nt++) {
        int n = n0 + nt * 16 + l16;
        int h = n >> 6, d = n & 63;
#pragma unroll
        for (int r = 0; r < 4; r++) {
            int row = r0 + w * 16 + quad * 4 + r;
            float val = vals[nt][r];
            if (MODE == 0) {
                int b = row >> sh, nloc = row & ((1 << sh) - 1);
                ((unsigned short*)dst)[((((size_t)(b * H_ + h) << sh) + nloc) << 6) + d] = f2bf(val);
            } else if (MODE == 1) {
                int b = row >> sh, nloc = row & ((1 << sh) - 1);
                ((unsigned short*)dst)[(((size_t)((b * H_ + h) * 64 + d)) << sh) + nloc] = f2bf(val);
            } else {
                ((float*)dst)[(size_t)row * 512 + n] = val;
            }
        }
    }
}

// ---------------------------------------------------------------------------
// Fused attention, ONLINE version (no 32x2048 Sp buffer -> 41 KB LDS -> 3 blk/CU).
// Per (bh, 32-row t-tile):
//   Phase 1 (per 128-c chunk): S = q̂k̂^T; p = exp(S) in regs (|S|<=1, no max
//     needed); accumulate row-sums in regs; drop p as bf16 into small Pt tile;
//     PV: oacc += Pt @ V^T (unnormalized).
//   Reduce: shfl + LDS cross-wave -> invs[32]; scale oacc, store oh.
//   Phase 3: re-stage K, recompute S (q frags still in regs), write
//     att = exp(S)*invs fp32 nontemporal (the mandatory 268 MB stream).
// ---------------------------------------------------------------------------
__global__ __launch_bounds__(256, 3) void attn_fused(const unsigned short* qh,
                                                     const unsigned short* kh,
                                                     const unsigned short* vt,
                                                     float* attout,
                                                     unsigned short* oh)
{
    __shared__ unsigned short Ks[128 * 64];    // 16 KB   K tile (c-major rows)
    __shared__ unsigned short Vs[2][64 * 64];  // 16 KB   V tile (d-major rows), 2 c-halves
    __shared__ unsigned short Pt[2][32 * 64];  // 8 KB    exp(S) tile, 2 c-halves
    __shared__ float red[4][32];
    __shared__ float invs[32];
    int bh = blockIdx.y;
    int t0 = blockIdx.x * 32;
    int tid = threadIdx.x;
    int w = tid >> 6, quad = (tid >> 4) & 3, l16 = tid & 15;

    // stage Q through the Pt area (free before phase 1 writes it)
    stage_bf<1>((unsigned short*)Pt, qh + ((size_t)bh * NT_ + t0) * 64, 64);
    __syncthreads();
    bf16x8 qf[2][2];
#pragma unroll
    for (int mt = 0; mt < 2; mt++)
#pragma unroll
        for (int ks = 0; ks < 2; ks++) qf[mt][ks] = ldfrag((unsigned short*)Pt, 16 * mt, 32 * ks);

    const unsigned short* kbase = kh + (size_t)bh * NC_ * 64;
    const unsigned short* vbase = vt + (size_t)bh * 64 * NC_;

    f32x4 oacc[2] = {};        // O rows 16*mt + quad*4 + r, d-col 16*w + l16
    float rs[2][4] = {};       // per-lane partial row sums [mt][r]

    // ---- phase 1: online QK^T -> exp -> rowsum + PV ----
    for (int c0 = 0; c0 < NC_; c0 += 128) {
        __syncthreads();
        stage_bf<4>(Ks, kbase + (size_t)c0 * 64, 64);
        stage_bf<2>(Vs[0], vbase + c0, NC_);
        stage_bf<2>(Vs[1], vbase + c0 + 64, NC_);
        __syncthreads();
#pragma unroll
        for (int nt = 0; nt < 2; nt++) {
            int cl = 32 * w + 16 * nt;         // local c base for this wave
            int half = cl >> 6, cc = cl & 63;
#pragma unroll
            for (int mt = 0; mt < 2; mt++) {
                f32x4 acc = {};
#pragma unroll
                for (int ks = 0; ks < 2; ks++) {
                    bf16x8 bfr = ldfrag(Ks, cl, 32 * ks);
                    acc = __builtin_amdgcn_mfma_f32_16x16x32_bf16(qf[mt][ks], bfr, acc, 0, 0, 0);
                }
#pragma unroll
                for (int r = 0; r < 4; r++) {
                    int t = 16 * mt + quad * 4 + r;
                    float p = __expf(acc[r]);
                    rs[mt][r] += p;
                    Pt[half][swz(t, cc + l16)] = f2bf(p);
                }
            }
        }
        __syncthreads();
#pragma unroll
        for (int half = 0; half < 2; half++) {
#pragma unroll
            for (int ks = 0; ks < 2; ks++) {
                bf16x8 vfr = ldfrag(Vs[half], 16 * w, 32 * ks);   // wave w owns d 16w..16w+15
#pragma unroll
                for (int mt = 0; mt < 2; mt++) {
                    bf16x8 af = ldfrag((unsigned short*)Pt[half], 16 * mt, 32 * ks);
                    oacc[mt] = __builtin_amdgcn_mfma_f32_16x16x32_bf16(af, vfr, oacc[mt], 0, 0, 0);
                }
            }
        }
    }

    // ---- rowsum reduce: l16 shfl (each wave covered disjoint c) + cross-wave LDS ----
#pragma unroll
    for (int mt = 0; mt < 2; mt++)
#pragma unroll
        for (int r = 0; r < 4; r++) {
            float s = rs[mt][r];
#pragma unroll
            for (int m = 1; m <= 8; m <<= 1) s += __shfl_xor(s, m, 64);
            if (l16 == 0) red[w][16 * mt + quad * 4 + r] = s;
        }
    __syncthreads();
    if (tid < 32) invs[tid] = 1.0f / (red[0][tid] + red[1][tid] + red[2][tid] + red[3][tid]);
    __syncthreads();

    // ---- O epilogue: scale by invs, store bf16 head-major ----
    {
        int b = bh >> 3, h = bh & 7;
        int d = 16 * w + l16;
#pragma unroll
        for (int mt = 0; mt < 2; mt++)
#pragma unroll
            for (int r = 0; r < 4; r++) {
                int t = 16 * mt + quad * 4 + r;
                oh[(size_t)(b * NT_ + t0 + t) * 512 + h * 64 + d] = f2bf(oacc[mt][r] * invs[t]);
            }
    }

    // ---- phase 3: recompute S, stream normalized att (fp32, nontemporal) ----
    float* attbase = attout + ((size_t)bh * NT_ + t0) * 2048;
    float myinv[2][4];
#pragma unroll
    for (int mt = 0; mt < 2; mt++)
#pragma unroll
        for (int r = 0; r < 4; r++) myinv[mt][r] = invs[16 * mt + quad * 4 + r];

    for (int c0 = 0; c0 < NC_; c0 += 128) {
        __syncthreads();
        stage_bf<4>(Ks, kbase + (size_t)c0 * 64, 64);
        __syncthreads();
#pragma unroll
        for (int nt = 0; nt < 2; nt++) {
            int cl = 32 * w + 16 * nt;
#pragma unroll
            for (int mt = 0; mt < 2; mt++) {
                f32x4 acc = {};
#pragma unroll
                for (int ks = 0; ks < 2; ks++) {
                    bf16x8 bfr = ldfrag(Ks, cl, 32 * ks);
                    acc = __builtin_amdgcn_mfma_f32_16x16x32_bf16(qf[mt][ks], bfr, acc, 0, 0, 0);
                }
#pragma unroll
                for (int r = 0; r < 4; r++) {
                    int t = 16 * mt + quad * 4 + r;
                    __builtin_nontemporal_store(__expf(acc[r]) * myinv[mt][r],
                                                attbase + (size_t)t * 2048 + c0 + cl + l16);
                }
            }
        }
    }
}

// ---------------------------------------------------------------------------
extern "C" void kernel_launch(void* const* d_in, const int* in_sizes, int n_in,
                              void* d_out, int out_size, void* d_ws, size_t ws_size,
                              hipStream_t stream)
{
    (void)in_sizes; (void)n_in; (void)out_size; (void)ws_size;
    const float* queries = (const float*)d_in[0];
    const float* keys    = (const float*)d_in[1];
    const float* values  = (const float*)d_in[2];
    const float* W_At    = (const float*)d_in[3];
    const float* b_At    = (const float*)d_in[4];
    const float* W_Ac    = (const float*)d_in[5];
    const float* b_Ac    = (const float*)d_in[6];
    const float* W_Bc    = (const float*)d_in[7];
    const float* b_Bc    = (const float*)d_in[8];
    const float* W_R     = (const float*)d_in[9];
    const float* b_R     = (const float*)d_in[10];

    float* out0   = (float*)d_out;
    float* attout = out0 + (size_t)B_ * NT_ * EMB_;

    unsigned short* ws = (unsigned short*)d_ws;
    unsigned short* qh = ws;                          // (B,H,NT,64) bf16, normalized
    unsigned short* kh = qh + (size_t)2097152;        // (B,H,NC,64) bf16, normalized
    unsigned short* vt = kh + (size_t)8388608;        // (B,H,64,NC) bf16 d-major
    unsigned short* oh = vt + (size_t)8388608;        // (B,NT,H*64) bf16

    dim3 blk(256);

    // projections (q/k with fused row-normalization in the epilogue)
    gemm512<0, false><<<dim3(4096 / 64, 8),  blk, 0, stream>>>(queries, W_At, b_At, qh, 9);
    gemm512<0, false><<<dim3(16384 / 64, 8), blk, 0, stream>>>(keys,    W_Ac, b_Ac, kh, 11);
    gemm512<1, false><<<dim3(16384 / 64, 8), blk, 0, stream>>>(values,  W_Bc, b_Bc, vt, 11);

    // fused scores + online softmax + PV, then att recompute-and-stream
    attn_fused<<<dim3(NT_ / 32, B_ * H_), blk, 0, stream>>>(qh, kh, vt, attout, oh);

    // out = O @ W_R^T + b_R
    gemm512<2, true><<<dim3(4096 / 64, 8), blk, 0, stream>>>(oh, W_R, b_R, out0, 0);
}

// Round 2
// 492.307 us; speedup vs baseline: 1.1003x; 1.0445x over previous
//
#include <hip/hip_runtime.h>

// Problem constants
#define B_   8
#define NT_  512
#define NC_  2048
#define EMB_ 512
#define H_   8
// DK = DV = 64

typedef __attribute__((ext_vector_type(8))) short bf16x8;
typedef __attribute__((ext_vector_type(4))) float f32x4;

__device__ __forceinline__ unsigned short f2bf(float x) {
    unsigned u = __float_as_uint(x);
    u += 0x7fffu + ((u >> 16) & 1u);          // RNE
    return (unsigned short)(u >> 16);
}
__device__ __forceinline__ float b2f(unsigned short h) {
    return __uint_as_float(((unsigned)h) << 16);
}
// 2x fp32 -> packed bf16x2 in one VALU op (RNE), gfx950-native.
__device__ __forceinline__ unsigned pkbf(float lo, float hi) {
    unsigned r;
    asm("v_cvt_pk_bf16_f32 %0, %1, %2" : "=v"(r) : "v"(lo), "v"(hi));
    return r;
}

// XOR-swizzled LDS tile index: rows of 64 bf16, 8-elem (16B) granules.
__device__ __forceinline__ int swz(int row, int col) {
    return row * 64 + ((((col >> 3) ^ row) & 7) << 3) + (col & 7);
}

// MFMA operand fragment from a swizzled 64-col tile:
// elem j of lane L holds T[rowbase + (L&15)][kq + (L>>4)*8 + j]
__device__ __forceinline__ bf16x8 ldfrag(const unsigned short* t, int rowbase, int kq) {
    int lane = threadIdx.x & 63;
    int m = rowbase + (lane & 15);
    int k = kq + ((lane >> 4) << 3);
    return *(const bf16x8*)(t + swz(m, k));
}

// Stage a 64-col x (NCH*32)-row tile into swizzled LDS from fp32 global (cvt bf16).
template<int NCH>
__device__ __forceinline__ void stage_f32(unsigned short* tile, const float* src, int ld) {
    int tid = threadIdx.x;
#pragma unroll
    for (int i = 0; i < NCH; i++) {
        int ch  = tid + i * 256;
        int row = ch >> 3, c8 = ch & 7;
        const float4* p = (const float4*)(src + (size_t)row * ld + c8 * 8);
        float4 a = p[0], b = p[1];
        uint4 u;
        u.x = pkbf(a.x, a.y);
        u.y = pkbf(a.z, a.w);
        u.z = pkbf(b.x, b.y);
        u.w = pkbf(b.z, b.w);
        *(uint4*)(tile + row * 64 + (((c8 ^ row) & 7) << 3)) = u;
    }
}
// Same, from bf16 global.
template<int NCH>
__device__ __forceinline__ void stage_bf(unsigned short* tile, const unsigned short* src, int ld) {
    int tid = threadIdx.x;
#pragma unroll
    for (int i = 0; i < NCH; i++) {
        int ch  = tid + i * 256;
        int row = ch >> 3, c8 = ch & 7;
        uint4 u = *(const uint4*)(src + (size_t)row * ld + c8 * 8);
        *(uint4*)(tile + row * 64 + (((c8 ^ row) & 7) << 3)) = u;
    }
}

// ---------------------------------------------------------------------------
// One-shot weight conversion: 4 matrices of 512x512 fp32 -> bf16 (row-major kept).
// ---------------------------------------------------------------------------
__global__ __launch_bounds__(256) void cvtw(const float* w0, const float* w1,
                                            const float* w2, const float* w3,
                                            unsigned short* dst)
{
    int idx = blockIdx.x * 256 + threadIdx.x;     // 131072 threads x 8 floats
    int m = idx >> 15;
    int off = (idx & 32767) * 8;
    const float* src = m == 0 ? w0 : m == 1 ? w1 : m == 2 ? w2 : w3;
    float4 a = ((const float4*)(src + off))[0];
    float4 b = ((const float4*)(src + off))[1];
    uint4 u;
    u.x = pkbf(a.x, a.y);
    u.y = pkbf(a.z, a.w);
    u.z = pkbf(b.x, b.y);
    u.w = pkbf(b.z, b.w);
    *(uint4*)(dst + (size_t)m * 262144 + off) = u;
}

// ---------------------------------------------------------------------------
// C = A(Mx512) @ W(512x512)^T + bias, 64x64 block tile, 4 waves. W is bf16.
// MODE 0: bf16 out, head-major, ROW-NORMALIZED (q/k projections; 64-n tile == one head)
// MODE 1: bf16 out, d-major transposed (v projection)
// MODE 2: fp32 out, row-major (final out projection)
// ---------------------------------------------------------------------------
template<int MODE, bool ABF>
__global__ __launch_bounds__(256, 4) void gemm512(const void* A, const unsigned short* W,
                                                  const float* bias, void* dst, int sh)
{
    __shared__ unsigned short As[64 * 64];
    __shared__ unsigned short Bs[64 * 64];
    int r0 = blockIdx.x * 64;
    int n0 = blockIdx.y * 64;
    int tid = threadIdx.x;
    int w = tid >> 6, quad = (tid >> 4) & 3, l16 = tid & 15;
    f32x4 acc[4] = {};

    for (int k0 = 0; k0 < 512; k0 += 64) {
        __syncthreads();
        if (ABF) stage_bf<2>(As, (const unsigned short*)A + (size_t)r0 * 512 + k0, 512);
        else     stage_f32<2>(As, (const float*)A + (size_t)r0 * 512 + k0, 512);
        stage_bf<2>(Bs, W + (size_t)n0 * 512 + k0, 512);
        __syncthreads();
#pragma unroll
        for (int ks = 0; ks < 2; ks++) {
            bf16x8 af = ldfrag(As, 16 * w, 32 * ks);
#pragma unroll
            for (int nt = 0; nt < 4; nt++) {
                bf16x8 bfr = ldfrag(Bs, 16 * nt, 32 * ks);
                acc[nt] = __builtin_amdgcn_mfma_f32_16x16x32_bf16(af, bfr, acc[nt], 0, 0, 0);
            }
        }
    }

    float vals[4][4];
    float bn[4];
#pragma unroll
    for (int nt = 0; nt < 4; nt++) bn[nt] = bias[n0 + nt * 16 + l16];
#pragma unroll
    for (int nt = 0; nt < 4; nt++)
#pragma unroll
        for (int r = 0; r < 4; r++) vals[nt][r] = acc[nt][r] + bn[nt];

    if (MODE == 0) {
        // fused row-normalize: row's 64 d-values live across l16 group x 4 nt regs
#pragma unroll
        for (int r = 0; r < 4; r++) {
            float ss = 0.f;
#pragma unroll
            for (int nt = 0; nt < 4; nt++) ss += vals[nt][r] * vals[nt][r];
#pragma unroll
            for (int m = 1; m <= 8; m <<= 1) ss += __shfl_xor(ss, m, 64);
            float sc = rsqrtf(fmaxf(ss, 1e-24f));
#pragma unroll
            for (int nt = 0; nt < 4; nt++) vals[nt][r] *= sc;
        }
    }

#pragma unroll
    for (int nt = 0; nt < 4; nt++) {
        int n = n0 + nt * 16 + l16;
        int h = n >> 6, d = n & 63;
#pragma unroll
        for (int r = 0; r < 4; r++) {
            int row = r0 + w * 16 + quad * 4 + r;
            float val = vals[nt][r];
            if (MODE == 0) {
                int b = row >> sh, nloc = row & ((1 << sh) - 1);
                ((unsigned short*)dst)[((((size_t)(b * H_ + h) << sh) + nloc) << 6) + d] = f2bf(val);
            } else if (MODE == 1) {
                int b = row >> sh, nloc = row & ((1 << sh) - 1);
                ((unsigned short*)dst)[(((size_t)((b * H_ + h) * 64 + d)) << sh) + nloc] = f2bf(val);
            } else {
                ((float*)dst)[(size_t)row * 512 + n] = val;
            }
        }
    }
}

// ---------------------------------------------------------------------------
// Fused attention, ONLINE version (no 32x2048 Sp buffer -> 41 KB LDS -> 3 blk/CU).
// Per (bh, 32-row t-tile):
//   Phase 1 (per 128-c chunk): S = q̂k̂^T; p = exp(S) in regs (|S|<=1, no max
//     needed); accumulate row-sums in regs; drop p as bf16 into small Pt tile;
//     PV: oacc += Pt @ V^T (unnormalized).
//   Reduce: shfl + LDS cross-wave -> invs[32]; scale oacc, store oh.
//   Phase 3: re-stage K, recompute S (q frags still in regs), write
//     att = exp(S)*invs fp32 nontemporal (the mandatory 268 MB stream).
// ---------------------------------------------------------------------------
__global__ __launch_bounds__(256, 3) void attn_fused(const unsigned short* qh,
                                                     const unsigned short* kh,
                                                     const unsigned short* vt,
                                                     float* attout,
                                                     unsigned short* oh)
{
    __shared__ unsigned short Ks[128 * 64];    // 16 KB   K tile (c-major rows)
    __shared__ unsigned short Vs[2][64 * 64];  // 16 KB   V tile (d-major rows), 2 c-halves
    __shared__ unsigned short Pt[2][32 * 64];  // 8 KB    exp(S) tile, 2 c-halves
    __shared__ float red[4][32];
    __shared__ float invs[32];
    int bh = blockIdx.y;
    int t0 = blockIdx.x * 32;
    int tid = threadIdx.x;
    int w = tid >> 6, quad = (tid >> 4) & 3, l16 = tid & 15;

    // stage Q through the Pt area (free before phase 1 writes it)
    stage_bf<1>((unsigned short*)Pt, qh + ((size_t)bh * NT_ + t0) * 64, 64);
    __syncthreads();
    bf16x8 qf[2][2];
#pragma unroll
    for (int mt = 0; mt < 2; mt++)
#pragma unroll
        for (int ks = 0; ks < 2; ks++) qf[mt][ks] = ldfrag((unsigned short*)Pt, 16 * mt, 32 * ks);

    const unsigned short* kbase = kh + (size_t)bh * NC_ * 64;
    const unsigned short* vbase = vt + (size_t)bh * 64 * NC_;

    f32x4 oacc[2] = {};        // O rows 16*mt + quad*4 + r, d-col 16*w + l16
    float rs[2][4] = {};       // per-lane partial row sums [mt][r]

    // ---- phase 1: online QK^T -> exp -> rowsum + PV ----
    for (int c0 = 0; c0 < NC_; c0 += 128) {
        __syncthreads();
        stage_bf<4>(Ks, kbase + (size_t)c0 * 64, 64);
        stage_bf<2>(Vs[0], vbase + c0, NC_);
        stage_bf<2>(Vs[1], vbase + c0 + 64, NC_);
        __syncthreads();
#pragma unroll
        for (int nt = 0; nt < 2; nt++) {
            int cl = 32 * w + 16 * nt;         // local c base for this wave
            int half = cl >> 6, cc = cl & 63;
#pragma unroll
            for (int mt = 0; mt < 2; mt++) {
                f32x4 acc = {};
#pragma unroll
                for (int ks = 0; ks < 2; ks++) {
                    bf16x8 bfr = ldfrag(Ks, cl, 32 * ks);
                    acc = __builtin_amdgcn_mfma_f32_16x16x32_bf16(qf[mt][ks], bfr, acc, 0, 0, 0);
                }
#pragma unroll
                for (int r = 0; r < 4; r++) {
                    int t = 16 * mt + quad * 4 + r;
                    float p = __expf(acc[r]);
                    rs[mt][r] += p;
                    Pt[half][swz(t, cc + l16)] = f2bf(p);
                }
            }
        }
        __syncthreads();
#pragma unroll
        for (int half = 0; half < 2; half++) {
#pragma unroll
            for (int ks = 0; ks < 2; ks++) {
                bf16x8 vfr = ldfrag(Vs[half], 16 * w, 32 * ks);   // wave w owns d 16w..16w+15
#pragma unroll
                for (int mt = 0; mt < 2; mt++) {
                    bf16x8 af = ldfrag((unsigned short*)Pt[half], 16 * mt, 32 * ks);
                    oacc[mt] = __builtin_amdgcn_mfma_f32_16x16x32_bf16(af, vfr, oacc[mt], 0, 0, 0);
                }
            }
        }
    }

    // ---- rowsum reduce: l16 shfl (each wave covered disjoint c) + cross-wave LDS ----
#pragma unroll
    for (int mt = 0; mt < 2; mt++)
#pragma unroll
        for (int r = 0; r < 4; r++) {
            float s = rs[mt][r];
#pragma unroll
            for (int m = 1; m <= 8; m <<= 1) s += __shfl_xor(s, m, 64);
            if (l16 == 0) red[w][16 * mt + quad * 4 + r] = s;
        }
    __syncthreads();
    if (tid < 32) invs[tid] = 1.0f / (red[0][tid] + red[1][tid] + red[2][tid] + red[3][tid]);
    __syncthreads();

    // ---- O epilogue: scale by invs, store bf16 head-major ----
    {
        int b = bh >> 3, h = bh & 7;
        int d = 16 * w + l16;
#pragma unroll
        for (int mt = 0; mt < 2; mt++)
#pragma unroll
            for (int r = 0; r < 4; r++) {
                int t = 16 * mt + quad * 4 + r;
                oh[(size_t)(b * NT_ + t0 + t) * 512 + h * 64 + d] = f2bf(oacc[mt][r] * invs[t]);
            }
    }

    // ---- phase 3: recompute S, stream normalized att (fp32, nontemporal) ----
    float* attbase = attout + ((size_t)bh * NT_ + t0) * 2048;
    float myinv[2][4];
#pragma unroll
    for (int mt = 0; mt < 2; mt++)
#pragma unroll
        for (int r = 0; r < 4; r++) myinv[mt][r] = invs[16 * mt + quad * 4 + r];

    for (int c0 = 0; c0 < NC_; c0 += 128) {
        __syncthreads();
        stage_bf<4>(Ks, kbase + (size_t)c0 * 64, 64);
        __syncthreads();
#pragma unroll
        for (int nt = 0; nt < 2; nt++) {
            int cl = 32 * w + 16 * nt;
#pragma unroll
            for (int mt = 0; mt < 2; mt++) {
                f32x4 acc = {};
#pragma unroll
                for (int ks = 0; ks < 2; ks++) {
                    bf16x8 bfr = ldfrag(Ks, cl, 32 * ks);
                    acc = __builtin_amdgcn_mfma_f32_16x16x32_bf16(qf[mt][ks], bfr, acc, 0, 0, 0);
                }
#pragma unroll
                for (int r = 0; r < 4; r++) {
                    int t = 16 * mt + quad * 4 + r;
                    __builtin_nontemporal_store(__expf(acc[r]) * myinv[mt][r],
                                                attbase + (size_t)t * 2048 + c0 + cl + l16);
                }
            }
        }
    }
}

// ---------------------------------------------------------------------------
extern "C" void kernel_launch(void* const* d_in, const int* in_sizes, int n_in,
                              void* d_out, int out_size, void* d_ws, size_t ws_size,
                              hipStream_t stream)
{
    (void)in_sizes; (void)n_in; (void)out_size; (void)ws_size;
    const float* queries = (const float*)d_in[0];
    const float* keys    = (const float*)d_in[1];
    const float* values  = (const float*)d_in[2];
    const float* W_At    = (const float*)d_in[3];
    const float* b_At    = (const float*)d_in[4];
    const float* W_Ac    = (const float*)d_in[5];
    const float* b_Ac    = (const float*)d_in[6];
    const float* W_Bc    = (const float*)d_in[7];
    const float* b_Bc    = (const float*)d_in[8];
    const float* W_R     = (const float*)d_in[9];
    const float* b_R     = (const float*)d_in[10];

    float* out0   = (float*)d_out;
    float* attout = out0 + (size_t)B_ * NT_ * EMB_;

    unsigned short* ws = (unsigned short*)d_ws;
    unsigned short* qh = ws;                          // (B,H,NT,64) bf16, normalized
    unsigned short* kh = qh + (size_t)2097152;        // (B,H,NC,64) bf16, normalized
    unsigned short* vt = kh + (size_t)8388608;        // (B,H,64,NC) bf16 d-major
    unsigned short* oh = vt + (size_t)8388608;        // (B,NT,H*64) bf16
    unsigned short* wb = oh + (size_t)2097152;        // 4 x (512x512) bf16 weights

    dim3 blk(256);

    // one-shot weight fp32->bf16 (W_At, W_Ac, W_Bc, W_R)
    cvtw<<<dim3(512), blk, 0, stream>>>(W_At, W_Ac, W_Bc, W_R, wb);

    // projections (q/k with fused row-normalization in the epilogue)
    gemm512<0, false><<<dim3(4096 / 64, 8),  blk, 0, stream>>>(queries, wb,               b_At, qh, 9);
    gemm512<0, false><<<dim3(16384 / 64, 8), blk, 0, stream>>>(keys,    wb + 262144,      b_Ac, kh, 11);
    gemm512<1, false><<<dim3(16384 / 64, 8), blk, 0, stream>>>(values,  wb + 2 * 262144,  b_Bc, vt, 11);

    // fused scores + online softmax + PV, then att recompute-and-stream
    attn_fused<<<dim3(NT_ / 32, B_ * H_), blk, 0, stream>>>(qh, kh, vt, attout, oh);

    // out = O @ W_R^T + b_R
    gemm512<2, true><<<dim3(4096 / 64, 8), blk, 0, stream>>>(oh, wb + 3 * 262144, b_R, out0, 0);
}